// Round 13
// baseline (185.638 us; speedup 1.0000x reference)
//
#include <hip/hip_runtime.h>
#include <hip/hip_bf16.h>

typedef __hip_bfloat16 bf16;

#define N_NODES 16384
#define D_IN    128
#define HID     64
#define HEADS   4
#define F1      256   // HEADS*HID
#define SEQ     128
#define SLOTS   64    // fixed CSR capacity per node (P(deg>64) ~ 1e-12 for this graph)

__device__ __forceinline__ float wave_sum(float v) {
    #pragma unroll
    for (int o = 32; o > 0; o >>= 1) v += __shfl_xor(v, o, 64);
    return v;
}
__device__ __forceinline__ float wave_max(float v) {
    #pragma unroll
    for (int o = 32; o > 0; o >>= 1) v = fmaxf(v, __shfl_xor(v, o, 64));
    return v;
}
__device__ __forceinline__ float lrelu(float v) { return v > 0.f ? v : 0.2f * v; }
__device__ __forceinline__ float rdlane(float v, int l) {
    return __uint_as_float(__builtin_amdgcn_readlane(__float_as_uint(v), l));
}

#define UNPACK8(u, te, acc)                                          \
    do {                                                             \
        acc[0] += (te) * __uint_as_float((u).x << 16);               \
        acc[1] += (te) * __uint_as_float((u).x & 0xffff0000u);       \
        acc[2] += (te) * __uint_as_float((u).y << 16);               \
        acc[3] += (te) * __uint_as_float((u).y & 0xffff0000u);       \
        acc[4] += (te) * __uint_as_float((u).z << 16);               \
        acc[5] += (te) * __uint_as_float((u).z & 0xffff0000u);       \
        acc[6] += (te) * __uint_as_float((u).w << 16);               \
        acc[7] += (te) * __uint_as_float((u).w & 0xffff0000u);       \
    } while (0)

// ---------------- D1: zero cnt (16 KB) ----------------
__global__ __launch_bounds__(256) void k_zero(int4* p) {
    p[blockIdx.x * 256 + threadIdx.x] = make_int4(0, 0, 0, 0);   // 16 x 256 x 16B
}

// ---------------- D2: scatter (blocks < eblocks) || gemm1 (+PE, +logits) ----------------
__global__ __launch_bounds__(256) void k_scatter_gemm1(
        const int* __restrict__ ei, int E, int Etot, int eblocks,
        int* __restrict__ cnt, int* __restrict__ esrc,
        const float* __restrict__ x, const float* __restrict__ pe,
        const float* __restrict__ W1,
        const float* __restrict__ a_src1, const float* __restrict__ a_dst1,
        bf16* __restrict__ h, float* __restrict__ as1, float* __restrict__ ad1) {
    int tid = threadIdx.x, lane = tid & 63, wv = tid >> 6;
    if ((int)blockIdx.x < eblocks) {
        int e = blockIdx.x * 256 + tid;
        if (e >= Etot) return;
        int s, d;
        if (e < E) { s = ei[e]; d = ei[E + e]; }
        else       { s = e - E; d = s; }
        int pos = atomicAdd(&cnt[d], 1);
        if (pos < SLOTS) esrc[d * SLOTS + pos] = s;
        return;
    }
    int base = (blockIdx.x - eblocks) * 16;
    int j4 = lane * 4;
    float2 xr[4];
    #pragma unroll
    for (int i = 0; i < 4; i++) {
        int row = base + wv * 4 + i;
        float2 xa  = *(const float2*)(x  + (size_t)row * 128 + 2 * lane);
        float2 pea = *(const float2*)(pe + (size_t)(row & (SEQ - 1)) * 128 + 2 * lane);
        xr[i].x = xa.x * 11.313708499f + pea.x;
        xr[i].y = xa.y * 11.313708499f + pea.y;
    }
    float acc[4][4] = {};
    const float4* Wv = (const float4*)W1;   // Wv[k*64 + lane] == W1[k*256 + lane*4]
    #pragma unroll 4
    for (int k2 = 0; k2 < 64; k2++) {
        float4 w0 = Wv[(size_t)(2 * k2) * 64 + lane];
        float4 w1 = Wv[(size_t)(2 * k2 + 1) * 64 + lane];
        #pragma unroll
        for (int i = 0; i < 4; i++) {
            float a0 = rdlane(xr[i].x, k2);
            float a1 = rdlane(xr[i].y, k2);
            acc[i][0] += a0 * w0.x + a1 * w1.x;
            acc[i][1] += a0 * w0.y + a1 * w1.y;
            acc[i][2] += a0 * w0.z + a1 * w1.z;
            acc[i][3] += a0 * w0.w + a1 * w1.w;
        }
    }
    float4 asv = *(const float4*)(a_src1 + j4);
    float4 adv = *(const float4*)(a_dst1 + j4);
    #pragma unroll
    for (int i = 0; i < 4; i++) {
        int row = base + wv * 4 + i;
        union { bf16 b[4]; ushort4 u; } cv;
        cv.b[0] = __float2bfloat16(acc[i][0]);
        cv.b[1] = __float2bfloat16(acc[i][1]);
        cv.b[2] = __float2bfloat16(acc[i][2]);
        cv.b[3] = __float2bfloat16(acc[i][3]);
        *(ushort4*)(h + (size_t)row * 256 + j4) = cv.u;
        float vs = acc[i][0] * asv.x + acc[i][1] * asv.y + acc[i][2] * asv.z + acc[i][3] * asv.w;
        float vd = acc[i][0] * adv.x + acc[i][1] * adv.y + acc[i][2] * adv.z + acc[i][3] * adv.w;
        #pragma unroll
        for (int o = 1; o < 16; o <<= 1) {
            vs += __shfl_xor(vs, o);
            vd += __shfl_xor(vd, o);
        }
        if ((lane & 15) == 0) {
            as1[row * 4 + (lane >> 4)] = vs;
            ad1[row * 4 + (lane >> 4)] = vd;
        }
    }
}

// ---------------- D3: fused agg1 + gemm2; paired-node interleaved gather ----------------
// grid 2048, 8 nodes/block; agg phase: wave = head, nodes processed in pairs so
// two gather chains are in flight; gemm2 phase: 2 rows/wave.
__global__ __launch_bounds__(256) void k_agg1_gemm2(
        const int* __restrict__ cnt, const int* __restrict__ esrc,
        const bf16* __restrict__ h,
        const float* __restrict__ as1, const float* __restrict__ ad1,
        const float* __restrict__ b1,
        const float* __restrict__ W2,
        const float* __restrict__ a_src2, const float* __restrict__ a_dst2,
        bf16* __restrict__ h2, float* __restrict__ as2, float* __restrict__ ad2) {
    __shared__ float hs[8][256];
    int tid = threadIdx.x, lane = tid & 63, wv = tid >> 6;
    int dbase = blockIdx.x * 8;

    int eg = lane >> 3;   // edge slot within octet group
    int cg_ = lane & 7;   // channel group (8 channels, 16 B)
    const bf16* hbase = h + (size_t)wv * 64 + cg_ * 8;

    for (int it = 0; it < 8; it += 2) {
        int dA = dbase + it, dB = dbase + it + 1;
        int degA = min(cnt[dA], SLOTS);
        int degB = min(cnt[dB], SLOTS);
        float adwA = ad1[dA * 4 + wv];
        float adwB = ad1[dB * 4 + wv];

        // prelude for both nodes (independent loads overlap)
        int sA = 0, sB = 0; float evA = -1e30f, evB = -1e30f;
        if (lane < degA) sA = esrc[dA * SLOTS + lane];
        if (lane < degB) sB = esrc[dB * SLOTS + lane];
        if (lane < degA) evA = lrelu(as1[sA * 4 + wv] + adwA);
        if (lane < degB) evB = lrelu(as1[sB * 4 + wv] + adwB);
        float mxA = wave_max(evA), mxB = wave_max(evB);
        float tA = (lane < degA) ? __expf(evA - mxA) : 0.f;
        float tB = (lane < degB) ? __expf(evB - mxB) : 0.f;
        float denA = wave_sum(tA), denB = wave_sum(tB);

        float accA[8] = {0, 0, 0, 0, 0, 0, 0, 0};
        float accB[8] = {0, 0, 0, 0, 0, 0, 0, 0};
        int degMax = max(degA, degB);
        for (int sub = 0; sub < degMax; sub += 32) {
            int qnA = (degA > sub) ? ((min(degA - sub, 32) + 7) >> 3) : 0;
            int qnB = (degB > sub) ? ((min(degB - sub, 32) + 7) >> 3) : 0;
            uint4 uA0, uA1, uA2, uA3, uB0, uB1, uB2, uB3;
            float teA0, teA1, teA2, teA3, teB0, teB1, teB2, teB3;
            // batched guarded loads for BOTH nodes before any unpack
            if (qnA > 0) {
                int se = __shfl(sA, sub + eg);      teA0 = __shfl(tA, sub + eg);
                uA0 = *(const uint4*)(hbase + (size_t)se * 256);
            }
            if (qnB > 0) {
                int se = __shfl(sB, sub + eg);      teB0 = __shfl(tB, sub + eg);
                uB0 = *(const uint4*)(hbase + (size_t)se * 256);
            }
            if (qnA > 1) {
                int se = __shfl(sA, sub + 8 + eg);  teA1 = __shfl(tA, sub + 8 + eg);
                uA1 = *(const uint4*)(hbase + (size_t)se * 256);
            }
            if (qnB > 1) {
                int se = __shfl(sB, sub + 8 + eg);  teB1 = __shfl(tB, sub + 8 + eg);
                uB1 = *(const uint4*)(hbase + (size_t)se * 256);
            }
            if (qnA > 2) {
                int se = __shfl(sA, sub + 16 + eg); teA2 = __shfl(tA, sub + 16 + eg);
                uA2 = *(const uint4*)(hbase + (size_t)se * 256);
            }
            if (qnB > 2) {
                int se = __shfl(sB, sub + 16 + eg); teB2 = __shfl(tB, sub + 16 + eg);
                uB2 = *(const uint4*)(hbase + (size_t)se * 256);
            }
            if (qnA > 3) {
                int se = __shfl(sA, sub + 24 + eg); teA3 = __shfl(tA, sub + 24 + eg);
                uA3 = *(const uint4*)(hbase + (size_t)se * 256);
            }
            if (qnB > 3) {
                int se = __shfl(sB, sub + 24 + eg); teB3 = __shfl(tB, sub + 24 + eg);
                uB3 = *(const uint4*)(hbase + (size_t)se * 256);
            }
            if (qnA > 0) UNPACK8(uA0, teA0, accA);
            if (qnB > 0) UNPACK8(uB0, teB0, accB);
            if (qnA > 1) UNPACK8(uA1, teA1, accA);
            if (qnB > 1) UNPACK8(uB1, teB1, accB);
            if (qnA > 2) UNPACK8(uA2, teA2, accA);
            if (qnB > 2) UNPACK8(uB2, teB2, accB);
            if (qnA > 3) UNPACK8(uA3, teA3, accA);
            if (qnB > 3) UNPACK8(uB3, teB3, accB);
        }
        #pragma unroll
        for (int j = 0; j < 8; j++) {
            accA[j] += __shfl_xor(accA[j], 8);
            accB[j] += __shfl_xor(accB[j], 8);
            accA[j] += __shfl_xor(accA[j], 16);
            accB[j] += __shfl_xor(accB[j], 16);
            accA[j] += __shfl_xor(accA[j], 32);
            accB[j] += __shfl_xor(accB[j], 32);
        }
        if (lane < 8) {
            int cbase = wv * 64 + lane * 8;
            float invA = 1.f / (denA + 1e-16f);
            float invB = 1.f / (denB + 1e-16f);
            float oA[8], oB[8];
            #pragma unroll
            for (int j = 0; j < 8; j++) {
                float bv = b1[cbase + j];
                float vA = accA[j] * invA + bv;
                float vB = accB[j] * invB + bv;
                oA[j] = vA > 0.f ? vA : (__expf(vA) - 1.f);   // elu
                oB[j] = vB > 0.f ? vB : (__expf(vB) - 1.f);
            }
            float4* dstA = (float4*)&hs[it][cbase];
            float4* dstB = (float4*)&hs[it + 1][cbase];
            dstA[0] = make_float4(oA[0], oA[1], oA[2], oA[3]);
            dstA[1] = make_float4(oA[4], oA[5], oA[6], oA[7]);
            dstB[0] = make_float4(oB[0], oB[1], oB[2], oB[3]);
            dstB[1] = make_float4(oB[4], oB[5], oB[6], oB[7]);
        }
    }
    __syncthreads();

    // ---- gemm2 on the 8 rows in LDS ----
    {
        int r0 = wv * 2, r1 = wv * 2 + 1;
        const float4* h0v = (const float4*)&hs[r0][0];
        const float4* h1v = (const float4*)&hs[r1][0];
        float a0 = 0.f, a1 = 0.f;
        #pragma unroll 4
        for (int k4 = 0; k4 < 64; k4++) {
            float4 u0 = h0v[k4];
            float4 u1 = h1v[k4];
            const float* wp = W2 + (size_t)k4 * 256 + lane;   // W2[(k4*4+q)*64 + lane]
            float w0 = wp[0], w1 = wp[64], w2 = wp[128], w3 = wp[192];
            a0 += u0.x * w0 + u0.y * w1 + u0.z * w2 + u0.w * w3;
            a1 += u1.x * w0 + u1.y * w1 + u1.z * w2 + u1.w * w3;
        }
        float asj = a_src2[lane], adj = a_dst2[lane];
        int n0 = dbase + r0, n1 = dbase + r1;
        h2[(size_t)n0 * 64 + lane] = __float2bfloat16(a0);
        h2[(size_t)n1 * 64 + lane] = __float2bfloat16(a1);
        float va0 = wave_sum(a0 * asj);
        float vd0 = wave_sum(a0 * adj);
        float va1 = wave_sum(a1 * asj);
        float vd1 = wave_sum(a1 * adj);
        if (lane == 0) {
            as2[n0] = va0; ad2[n0] = vd0;
            as2[n1] = va1; ad2[n1] = vd1;
        }
    }
}

// ---------------- D4: agg2 -> out; octet-skipping gather ----------------
__global__ __launch_bounds__(256) void k_agg2(const int* __restrict__ cnt,
                                              const int* __restrict__ esrc,
                                              const bf16* __restrict__ h2,
                                              const float* __restrict__ as2,
                                              const float* __restrict__ ad2,
                                              const float* __restrict__ b2v,
                                              float* __restrict__ out) {
    int tid = threadIdx.x, lane = tid & 63, wv = tid >> 6;
    int d = blockIdx.x * 4 + wv;
    int deg = min(cnt[d], SLOTS);
    float adw = ad2[d];
    int eg = lane >> 3, cg_ = lane & 7;
    const bf16* hbase = h2 + cg_ * 8;

    int s = 0; float ev = -1e30f;
    if (lane < deg) {
        s = esrc[d * SLOTS + lane];
        ev = lrelu(as2[s] + adw);
    }
    float mx = wave_max(ev);
    float t = (lane < deg) ? __expf(ev - mx) : 0.f;
    float den = wave_sum(t);

    float acc[8] = {0, 0, 0, 0, 0, 0, 0, 0};
    for (int sub = 0; sub < deg; sub += 32) {
        int qn = (min(deg - sub, 32) + 7) >> 3;
        int se0, se1, se2, se3; float te0, te1, te2, te3;
        uint4 u0, u1, u2, u3;
        se0 = __shfl(s, sub + eg);      te0 = __shfl(t, sub + eg);
        u0 = *(const uint4*)(hbase + (size_t)se0 * 64);
        if (qn > 1) {
            se1 = __shfl(s, sub + 8 + eg);  te1 = __shfl(t, sub + 8 + eg);
            u1 = *(const uint4*)(hbase + (size_t)se1 * 64);
        }
        if (qn > 2) {
            se2 = __shfl(s, sub + 16 + eg); te2 = __shfl(t, sub + 16 + eg);
            u2 = *(const uint4*)(hbase + (size_t)se2 * 64);
        }
        if (qn > 3) {
            se3 = __shfl(s, sub + 24 + eg); te3 = __shfl(t, sub + 24 + eg);
            u3 = *(const uint4*)(hbase + (size_t)se3 * 64);
        }
        UNPACK8(u0, te0, acc);
        if (qn > 1) UNPACK8(u1, te1, acc);
        if (qn > 2) UNPACK8(u2, te2, acc);
        if (qn > 3) UNPACK8(u3, te3, acc);
    }
    #pragma unroll
    for (int j = 0; j < 8; j++) {
        acc[j] += __shfl_xor(acc[j], 8);
        acc[j] += __shfl_xor(acc[j], 16);
        acc[j] += __shfl_xor(acc[j], 32);
    }
    if (lane < 8) {
        float inv = 1.f / (den + 1e-16f);
        int cbase = lane * 8;
        float o[8];
        #pragma unroll
        for (int j = 0; j < 8; j++) o[j] = acc[j] * inv + b2v[cbase + j];
        float4* dst = (float4*)(out + (size_t)d * 64 + cbase);
        dst[0] = make_float4(o[0], o[1], o[2], o[3]);
        dst[1] = make_float4(o[4], o[5], o[6], o[7]);
    }
}

extern "C" void kernel_launch(void* const* d_in, const int* in_sizes, int n_in,
                              void* d_out, int out_size, void* d_ws, size_t ws_size,
                              hipStream_t stream) {
    const float* x    = (const float*)d_in[0];
    const int*   ei   = (const int*)  d_in[1];
    const float* pe   = (const float*)d_in[2];
    const float* W1   = (const float*)d_in[3];
    const float* a_s1 = (const float*)d_in[4];
    const float* a_d1 = (const float*)d_in[5];
    const float* b1   = (const float*)d_in[6];
    const float* W2   = (const float*)d_in[7];
    const float* a_s2 = (const float*)d_in[8];
    const float* a_d2 = (const float*)d_in[9];
    const float* b2   = (const float*)d_in[10];

    const int E    = in_sizes[1] / 2;
    const int n    = N_NODES;
    const int Etot = E + n;

    // workspace carve-up (256B aligned)
    char* p = (char*)d_ws;
    auto alloc = [&](size_t bytes) -> void* {
        void* r = (void*)p;
        p += (bytes + 255) & ~(size_t)255;
        return r;
    };
    int*   cnt     = (int*)  alloc((size_t)n * 4);
    int*   esrc    = (int*)  alloc((size_t)n * SLOTS * 4);
    bf16*  h       = (bf16*) alloc((size_t)n * F1 * 2);
    float* as1     = (float*)alloc((size_t)n * HEADS * 4);
    float* ad1     = (float*)alloc((size_t)n * HEADS * 4);
    bf16*  h2      = (bf16*) alloc((size_t)n * HID * 2);
    float* as2     = (float*)alloc((size_t)n * 4);
    float* ad2     = (float*)alloc((size_t)n * 4);

    int eblocks = (Etot + 255) / 256;

    k_zero         <<<n / (256 * 4), 256, 0, stream>>>((int4*)cnt);
    k_scatter_gemm1<<<eblocks + n / 16, 256, 0, stream>>>(
        ei, E, Etot, eblocks, cnt, esrc,
        x, pe, W1, a_s1, a_d1, h, as1, ad1);
    k_agg1_gemm2   <<<n / 8, 256, 0, stream>>>(cnt, esrc, h, as1, ad1, b1,
                                               W2, a_s2, a_d2, h2, as2, ad2);
    k_agg2         <<<n / 4, 256, 0, stream>>>(cnt, esrc, h2, as2, ad2, b2, (float*)d_out);
}

// Round 14
// 180.364 us; speedup vs baseline: 1.0292x; 1.0292x over previous
//
#include <hip/hip_runtime.h>
#include <hip/hip_bf16.h>

typedef __hip_bfloat16 bf16;

#define N_NODES 16384
#define D_IN    128
#define HID     64
#define HEADS   4
#define F1      256   // HEADS*HID
#define SEQ     128
#define SLOTS   64    // fixed CSR capacity per node (P(deg>64) ~ 1e-12 for this graph)

__device__ __forceinline__ float wave_sum(float v) {
    #pragma unroll
    for (int o = 32; o > 0; o >>= 1) v += __shfl_xor(v, o, 64);
    return v;
}
__device__ __forceinline__ float wave_max(float v) {
    #pragma unroll
    for (int o = 32; o > 0; o >>= 1) v = fmaxf(v, __shfl_xor(v, o, 64));
    return v;
}
__device__ __forceinline__ float lrelu(float v) { return v > 0.f ? v : 0.2f * v; }
__device__ __forceinline__ float rdlane(float v, int l) {
    return __uint_as_float(__builtin_amdgcn_readlane(__float_as_uint(v), l));
}

#define UNPACK8(u, te, acc)                                          \
    do {                                                             \
        acc[0] += (te) * __uint_as_float((u).x << 16);               \
        acc[1] += (te) * __uint_as_float((u).x & 0xffff0000u);       \
        acc[2] += (te) * __uint_as_float((u).y << 16);               \
        acc[3] += (te) * __uint_as_float((u).y & 0xffff0000u);       \
        acc[4] += (te) * __uint_as_float((u).z << 16);               \
        acc[5] += (te) * __uint_as_float((u).z & 0xffff0000u);       \
        acc[6] += (te) * __uint_as_float((u).w << 16);               \
        acc[7] += (te) * __uint_as_float((u).w & 0xffff0000u);       \
    } while (0)

// ---------------- D1: gemm1 (+PE, +logits) + cnt zeroing (R10 known-good) ----------------
// grid 1024, 16 rows/block, 4 rows/wave; x in registers, W1 streamed float4.
__global__ __launch_bounds__(256) void k_gemm1z(const float* __restrict__ x,
                                                const float* __restrict__ pe,
                                                const float* __restrict__ W1,
                                                const float* __restrict__ a_src1,
                                                const float* __restrict__ a_dst1,
                                                bf16* __restrict__ h,
                                                float* __restrict__ as1,
                                                float* __restrict__ ad1,
                                                int4* __restrict__ cntv) {
    int tid = threadIdx.x, lane = tid & 63, wv = tid >> 6;
    if (tid < 4) cntv[blockIdx.x * 4 + tid] = make_int4(0, 0, 0, 0);

    int base = blockIdx.x * 16;
    int j4 = lane * 4;
    float2 xr[4];
    #pragma unroll
    for (int i = 0; i < 4; i++) {
        int row = base + wv * 4 + i;
        float2 xa  = *(const float2*)(x  + (size_t)row * 128 + 2 * lane);
        float2 pea = *(const float2*)(pe + (size_t)(row & (SEQ - 1)) * 128 + 2 * lane);
        xr[i].x = xa.x * 11.313708499f + pea.x;
        xr[i].y = xa.y * 11.313708499f + pea.y;
    }
    float acc[4][4] = {};
    const float4* Wv = (const float4*)W1;   // Wv[k*64 + lane] == W1[k*256 + lane*4]
    #pragma unroll 4
    for (int k2 = 0; k2 < 64; k2++) {
        float4 w0 = Wv[(size_t)(2 * k2) * 64 + lane];
        float4 w1 = Wv[(size_t)(2 * k2 + 1) * 64 + lane];
        #pragma unroll
        for (int i = 0; i < 4; i++) {
            float a0 = rdlane(xr[i].x, k2);
            float a1 = rdlane(xr[i].y, k2);
            acc[i][0] += a0 * w0.x + a1 * w1.x;
            acc[i][1] += a0 * w0.y + a1 * w1.y;
            acc[i][2] += a0 * w0.z + a1 * w1.z;
            acc[i][3] += a0 * w0.w + a1 * w1.w;
        }
    }
    float4 asv = *(const float4*)(a_src1 + j4);
    float4 adv = *(const float4*)(a_dst1 + j4);
    #pragma unroll
    for (int i = 0; i < 4; i++) {
        int row = base + wv * 4 + i;
        union { bf16 b[4]; ushort4 u; } cv;
        cv.b[0] = __float2bfloat16(acc[i][0]);
        cv.b[1] = __float2bfloat16(acc[i][1]);
        cv.b[2] = __float2bfloat16(acc[i][2]);
        cv.b[3] = __float2bfloat16(acc[i][3]);
        *(ushort4*)(h + (size_t)row * 256 + j4) = cv.u;
        float vs = acc[i][0] * asv.x + acc[i][1] * asv.y + acc[i][2] * asv.z + acc[i][3] * asv.w;
        float vd = acc[i][0] * adv.x + acc[i][1] * adv.y + acc[i][2] * adv.z + acc[i][3] * adv.w;
        #pragma unroll
        for (int o = 1; o < 16; o <<= 1) {
            vs += __shfl_xor(vs, o);
            vd += __shfl_xor(vd, o);
        }
        if ((lane & 15) == 0) {
            as1[row * 4 + (lane >> 4)] = vs;
            ad1[row * 4 + (lane >> 4)] = vd;
        }
    }
}

// ---------------- D2: edge scatter (own dispatch, full occupancy) ----------------
__global__ __launch_bounds__(256) void k_scatter(const int* __restrict__ ei, int E, int Etot,
                                                 int* __restrict__ cnt,
                                                 int* __restrict__ esrc) {
    int e = blockIdx.x * 256 + threadIdx.x;
    if (e >= Etot) return;
    int s, d;
    if (e < E) { s = ei[e]; d = ei[E + e]; }
    else       { s = e - E; d = s; }
    int pos = atomicAdd(&cnt[d], 1);
    if (pos < SLOTS) esrc[d * SLOTS + pos] = s;
}

// ---------------- D3: fused agg1 + gemm2; octet-skipping gather (R12 known-good) ----------------
// grid 2048, 8 nodes/block; agg phase: wave = head; gemm2 phase: 2 rows/wave.
// NOTE (kernel law, R11/R13): this kernel is TLP-bound at 8 blocks/CU — do NOT
// add ILP that raises VGPR above ~40; occupancy loss dominates every time.
__global__ __launch_bounds__(256) void k_agg1_gemm2(
        const int* __restrict__ cnt, const int* __restrict__ esrc,
        const bf16* __restrict__ h,
        const float* __restrict__ as1, const float* __restrict__ ad1,
        const float* __restrict__ b1,
        const float* __restrict__ W2,
        const float* __restrict__ a_src2, const float* __restrict__ a_dst2,
        bf16* __restrict__ h2, float* __restrict__ as2, float* __restrict__ ad2) {
    __shared__ float hs[8][256];
    int tid = threadIdx.x, lane = tid & 63, wv = tid >> 6;
    int dbase = blockIdx.x * 8;

    int eg = lane >> 3;   // edge slot within octet group
    int cg_ = lane & 7;   // channel group (8 channels, 16 B)
    const bf16* hbase = h + (size_t)wv * 64 + cg_ * 8;

    #pragma unroll 2
    for (int it = 0; it < 8; it++) {
        int d = dbase + it;
        int deg = min(cnt[d], SLOTS);
        float adw = ad1[d * 4 + wv];

        int s = 0; float ev = -1e30f;
        if (lane < deg) {
            s = esrc[d * SLOTS + lane];
            ev = lrelu(as1[s * 4 + wv] + adw);
        }
        float mx = wave_max(ev);
        float t = (lane < deg) ? __expf(ev - mx) : 0.f;
        float den = wave_sum(t);

        float acc[8] = {0, 0, 0, 0, 0, 0, 0, 0};
        for (int sub = 0; sub < deg; sub += 32) {
            int qn = (min(deg - sub, 32) + 7) >> 3;   // 1..4 octets used, wave-uniform
            int se0, se1, se2, se3; float te0, te1, te2, te3;
            uint4 u0, u1, u2, u3;
            se0 = __shfl(s, sub + eg);      te0 = __shfl(t, sub + eg);
            u0 = *(const uint4*)(hbase + (size_t)se0 * 256);
            if (qn > 1) {
                se1 = __shfl(s, sub + 8 + eg);  te1 = __shfl(t, sub + 8 + eg);
                u1 = *(const uint4*)(hbase + (size_t)se1 * 256);
            }
            if (qn > 2) {
                se2 = __shfl(s, sub + 16 + eg); te2 = __shfl(t, sub + 16 + eg);
                u2 = *(const uint4*)(hbase + (size_t)se2 * 256);
            }
            if (qn > 3) {
                se3 = __shfl(s, sub + 24 + eg); te3 = __shfl(t, sub + 24 + eg);
                u3 = *(const uint4*)(hbase + (size_t)se3 * 256);
            }
            UNPACK8(u0, te0, acc);
            if (qn > 1) UNPACK8(u1, te1, acc);
            if (qn > 2) UNPACK8(u2, te2, acc);
            if (qn > 3) UNPACK8(u3, te3, acc);
        }
        #pragma unroll
        for (int j = 0; j < 8; j++) {
            acc[j] += __shfl_xor(acc[j], 8);
            acc[j] += __shfl_xor(acc[j], 16);
            acc[j] += __shfl_xor(acc[j], 32);
        }
        if (lane < 8) {
            float inv = 1.f / (den + 1e-16f);
            int cbase = wv * 64 + lane * 8;
            float o[8];
            #pragma unroll
            for (int j = 0; j < 8; j++) {
                float v = acc[j] * inv + b1[cbase + j];
                o[j] = v > 0.f ? v : (__expf(v) - 1.f);   // elu
            }
            float4* dst = (float4*)&hs[it][cbase];
            dst[0] = make_float4(o[0], o[1], o[2], o[3]);
            dst[1] = make_float4(o[4], o[5], o[6], o[7]);
        }
    }
    __syncthreads();

    // ---- gemm2 on the 8 rows in LDS ----
    {
        int r0 = wv * 2, r1 = wv * 2 + 1;
        const float4* h0v = (const float4*)&hs[r0][0];
        const float4* h1v = (const float4*)&hs[r1][0];
        float a0 = 0.f, a1 = 0.f;
        #pragma unroll 4
        for (int k4 = 0; k4 < 64; k4++) {
            float4 u0 = h0v[k4];
            float4 u1 = h1v[k4];
            const float* wp = W2 + (size_t)k4 * 256 + lane;   // W2[(k4*4+q)*64 + lane]
            float w0 = wp[0], w1 = wp[64], w2 = wp[128], w3 = wp[192];
            a0 += u0.x * w0 + u0.y * w1 + u0.z * w2 + u0.w * w3;
            a1 += u1.x * w0 + u1.y * w1 + u1.z * w2 + u1.w * w3;
        }
        float asj = a_src2[lane], adj = a_dst2[lane];
        int n0 = dbase + r0, n1 = dbase + r1;
        h2[(size_t)n0 * 64 + lane] = __float2bfloat16(a0);
        h2[(size_t)n1 * 64 + lane] = __float2bfloat16(a1);
        float va0 = wave_sum(a0 * asj);
        float vd0 = wave_sum(a0 * adj);
        float va1 = wave_sum(a1 * asj);
        float vd1 = wave_sum(a1 * adj);
        if (lane == 0) {
            as2[n0] = va0; ad2[n0] = vd0;
            as2[n1] = va1; ad2[n1] = vd1;
        }
    }
}

// ---------------- D4: agg2 -> out; octet-skipping gather (R12 known-good) ----------------
__global__ __launch_bounds__(256) void k_agg2(const int* __restrict__ cnt,
                                              const int* __restrict__ esrc,
                                              const bf16* __restrict__ h2,
                                              const float* __restrict__ as2,
                                              const float* __restrict__ ad2,
                                              const float* __restrict__ b2v,
                                              float* __restrict__ out) {
    int tid = threadIdx.x, lane = tid & 63, wv = tid >> 6;
    int d = blockIdx.x * 4 + wv;
    int deg = min(cnt[d], SLOTS);
    float adw = ad2[d];
    int eg = lane >> 3, cg_ = lane & 7;
    const bf16* hbase = h2 + cg_ * 8;

    int s = 0; float ev = -1e30f;
    if (lane < deg) {
        s = esrc[d * SLOTS + lane];
        ev = lrelu(as2[s] + adw);
    }
    float mx = wave_max(ev);
    float t = (lane < deg) ? __expf(ev - mx) : 0.f;
    float den = wave_sum(t);

    float acc[8] = {0, 0, 0, 0, 0, 0, 0, 0};
    for (int sub = 0; sub < deg; sub += 32) {
        int qn = (min(deg - sub, 32) + 7) >> 3;
        int se0, se1, se2, se3; float te0, te1, te2, te3;
        uint4 u0, u1, u2, u3;
        se0 = __shfl(s, sub + eg);      te0 = __shfl(t, sub + eg);
        u0 = *(const uint4*)(hbase + (size_t)se0 * 64);
        if (qn > 1) {
            se1 = __shfl(s, sub + 8 + eg);  te1 = __shfl(t, sub + 8 + eg);
            u1 = *(const uint4*)(hbase + (size_t)se1 * 64);
        }
        if (qn > 2) {
            se2 = __shfl(s, sub + 16 + eg); te2 = __shfl(t, sub + 16 + eg);
            u2 = *(const uint4*)(hbase + (size_t)se2 * 64);
        }
        if (qn > 3) {
            se3 = __shfl(s, sub + 24 + eg); te3 = __shfl(t, sub + 24 + eg);
            u3 = *(const uint4*)(hbase + (size_t)se3 * 64);
        }
        UNPACK8(u0, te0, acc);
        if (qn > 1) UNPACK8(u1, te1, acc);
        if (qn > 2) UNPACK8(u2, te2, acc);
        if (qn > 3) UNPACK8(u3, te3, acc);
    }
    #pragma unroll
    for (int j = 0; j < 8; j++) {
        acc[j] += __shfl_xor(acc[j], 8);
        acc[j] += __shfl_xor(acc[j], 16);
        acc[j] += __shfl_xor(acc[j], 32);
    }
    if (lane < 8) {
        float inv = 1.f / (den + 1e-16f);
        int cbase = lane * 8;
        float o[8];
        #pragma unroll
        for (int j = 0; j < 8; j++) o[j] = acc[j] * inv + b2v[cbase + j];
        float4* dst = (float4*)(out + (size_t)d * 64 + cbase);
        dst[0] = make_float4(o[0], o[1], o[2], o[3]);
        dst[1] = make_float4(o[4], o[5], o[6], o[7]);
    }
}

extern "C" void kernel_launch(void* const* d_in, const int* in_sizes, int n_in,
                              void* d_out, int out_size, void* d_ws, size_t ws_size,
                              hipStream_t stream) {
    const float* x    = (const float*)d_in[0];
    const int*   ei   = (const int*)  d_in[1];
    const float* pe   = (const float*)d_in[2];
    const float* W1   = (const float*)d_in[3];
    const float* a_s1 = (const float*)d_in[4];
    const float* a_d1 = (const float*)d_in[5];
    const float* b1   = (const float*)d_in[6];
    const float* W2   = (const float*)d_in[7];
    const float* a_s2 = (const float*)d_in[8];
    const float* a_d2 = (const float*)d_in[9];
    const float* b2   = (const float*)d_in[10];

    const int E    = in_sizes[1] / 2;
    const int n    = N_NODES;
    const int Etot = E + n;

    // workspace carve-up (256B aligned)
    char* p = (char*)d_ws;
    auto alloc = [&](size_t bytes) -> void* {
        void* r = (void*)p;
        p += (bytes + 255) & ~(size_t)255;
        return r;
    };
    int*   cnt     = (int*)  alloc((size_t)n * 4);
    int*   esrc    = (int*)  alloc((size_t)n * SLOTS * 4);
    bf16*  h       = (bf16*) alloc((size_t)n * F1 * 2);
    float* as1     = (float*)alloc((size_t)n * HEADS * 4);
    float* ad1     = (float*)alloc((size_t)n * HEADS * 4);
    bf16*  h2      = (bf16*) alloc((size_t)n * HID * 2);
    float* as2     = (float*)alloc((size_t)n * 4);
    float* ad2     = (float*)alloc((size_t)n * 4);

    int eblocks = (Etot + 255) / 256;

    k_gemm1z    <<<n / 16, 256, 0, stream>>>(x, pe, W1, a_s1, a_d1, h, as1, ad1, (int4*)cnt);
    k_scatter   <<<eblocks, 256, 0, stream>>>(ei, E, Etot, cnt, esrc);
    k_agg1_gemm2<<<n / 8, 256, 0, stream>>>(cnt, esrc, h, as1, ad1, b1,
                                            W2, a_s2, a_d2, h2, as2, ad2);
    k_agg2      <<<n / 4, 256, 0, stream>>>(cnt, esrc, h2, as2, ad2, b2, (float*)d_out);
}